// Round 9
// baseline (681.454 us; speedup 1.0000x reference)
//
#include <hip/hip_runtime.h>
#include <hip/hip_bf16.h>
#include <stdint.h>

// SpatioConvLayer: out = relu(x + b + einsum('iok,knm,bitm->botn', theta, Lk, x))
// (1) BT[n][k*1024+m] = bf16(Lk[k][n][m]); (2) Y[(b*48+t)*64+o][k*1024+m]
//     = sum_i theta[i,o,k] * x[b,i,t,m] (bf16, MFMA, LDS-staged x); (3) out =
//     Y @ BT^T fused bias+residual+relu.
// R8 k_gemm: 256x256x64, mfma 32x32x16 (half the instrs, 1.2x pipe rate),
//     B-frags DIRECT from global (BT is L2-resident; no B-LDS, no B-barriers),
//     A 3-deep LDS buffer (96KB) staged 2 tiles ahead, 2 barriers/tile,
//     no manual vmcnt in loop (in-order vmcnt retirement + compiler B-waits).
// R9 = R8 resubmitted verbatim (R8 bench was an infra failure, no data).

typedef short bs8 __attribute__((ext_vector_type(8)));    // 8 x bf16 fragment
typedef float f32x4 __attribute__((ext_vector_type(4)));  // 16x16 accumulator
typedef float f32x16 __attribute__((ext_vector_type(16))); // 32x32 accumulator

#define NB   16
#define NC   64
#define NT   48
#define NN   1024
#define NKS  3
#define KDIM 3072  // NKS * NN
#define KT   48    // KDIM / 64 K-tiles

// f32 -> bf16 round-to-nearest-even (finite inputs only)
__device__ __forceinline__ short f2bs(float f) {
  uint32_t u = __builtin_bit_cast(uint32_t, f);
  u = (u + 0x7FFFu + ((u >> 16) & 1u)) >> 16;
  return (short)u;
}

__device__ __forceinline__ void gload16(const void* g, void* l) {
  __builtin_amdgcn_global_load_lds(
      (const __attribute__((address_space(1))) void*)g,
      (__attribute__((address_space(3))) void*)l, 16, 0, 0);
}

// ---------------- prep: BT[n][k*NN+m] = bf16(Lk[k][n][m]) -------------------
__global__ __launch_bounds__(256) void k_prep_bt(const float* __restrict__ Lk,
                                                 short* __restrict__ BT) {
  int gid = blockIdx.x * 256 + threadIdx.x;
  int e = gid * 4;
  int k = e >> 20;
  int rem = e & 1048575;
  int n = rem >> 10;
  int m = rem & 1023;
  float4 v = *reinterpret_cast<const float4*>(Lk + e);
  union { short s[4]; uint64_t u; } p;
  p.s[0] = f2bs(v.x); p.s[1] = f2bs(v.y); p.s[2] = f2bs(v.z); p.s[3] = f2bs(v.w);
  *reinterpret_cast<uint64_t*>(BT + (size_t)n * KDIM + k * NN + m) = p.u;
}

// ---------------- step1: Y[btl*64+o][k*NN+m] = sum_i th[i,o,k] x[b,i,t,m] ---
__global__ __launch_bounds__(256, 2) void k_step1(const float* __restrict__ x,
                                                  const float* __restrict__ theta,
                                                  short* __restrict__ Y, int b0) {
  __shared__ __align__(16) short th[NKS * 64 * 72];  // [k][o][i] padded, 27.6KB
  __shared__ __align__(16) float xs[64 * 128];       // [i][m] slice, 32KB
  int tid = threadIdx.x;
  int wave = tid >> 6;
  for (int idx = tid; idx < NC * NC * NKS; idx += 256) {
    int i = idx / (NC * NKS);
    int r = idx - i * (NC * NKS);
    int o = r / NKS;
    int k = r - o * NKS;
    th[(k * 64 + o) * 72 + i] = f2bs(theta[idx]);  // theta[i][o][k]
  }

  int bid = blockIdx.x;
  int mt  = bid & 7;            // m-tile of 128
  int btl = bid >> 3;
  int b_l = btl / NT;
  int t   = btl - b_l * NT;
  int b   = b0 + b_l;
  const float* xb = x + (size_t)b * (NC * NT * NN) + (size_t)t * NN + mt * 128;

#pragma unroll
  for (int c = 0; c < 8; ++c) {
    int idx = c * 256 + tid;
    int row = idx >> 5, ch = idx & 31;
    gload16(xb + (size_t)row * (NT * NN) + ch * 4,
            xs + (c * 256 + wave * 64) * 4);  // wave-uniform base, 16B/lane
  }
  __syncthreads();  // drains vmcnt (xs) + lgkm (th)

  int lane = tid & 63;
  int l15 = lane & 15, lg = lane >> 4;
  size_t yrow0 = (size_t)btl * 64;

  for (int nni = 0; nni < 2; ++nni) {
    int mloc = wave * 32 + nni * 16 + l15;
    float xv[16];
#pragma unroll
    for (int j = 0; j < 16; ++j) {
      int i = ((j >> 3) << 5) + lg * 8 + (j & 7);
      xv[j] = xs[i * 128 + mloc];
    }
    f32x4 acc[3][4];
#pragma unroll
    for (int k = 0; k < 3; ++k)
#pragma unroll
      for (int mi = 0; mi < 4; ++mi)
        acc[k][mi] = (f32x4){0.f, 0.f, 0.f, 0.f};

#pragma unroll
    for (int ks = 0; ks < 2; ++ks) {
      bs8 bfrag;
#pragma unroll
      for (int j = 0; j < 8; ++j) bfrag[j] = f2bs(xv[ks * 8 + j]);
#pragma unroll
      for (int mi = 0; mi < 4; ++mi) {
#pragma unroll
        for (int k = 0; k < 3; ++k) {
          const bs8* ap = reinterpret_cast<const bs8*>(
              &th[(k * 64 + mi * 16 + l15) * 72 + ks * 32 + lg * 8]);
          acc[k][mi] = __builtin_amdgcn_mfma_f32_16x16x32_bf16(
              *ap, bfrag, acc[k][mi], 0, 0, 0);
        }
      }
    }
    int mcol = mt * 128 + mloc;
#pragma unroll
    for (int k = 0; k < 3; ++k)
#pragma unroll
      for (int mi = 0; mi < 4; ++mi)
#pragma unroll
        for (int q = 0; q < 4; ++q) {
          int o = mi * 16 + lg * 4 + q;
          Y[(yrow0 + o) * KDIM + k * NN + mcol] = f2bs(acc[k][mi][q]);
        }
  }
}

// ---------------- big GEMM: C = Y @ BT^T, 32x32x16, B-direct, A 3-buf -------
// 8 waves 2M x 4N. Wave output 128x64: M-frags(32) {4P+2e+wr}, N-frags(32)
// {4i+wc}. Per tile: [issue 8 B b128 (global, L2) + read A-half0 (8 ds_read)]
// BAR0 [stage A(t+2) (4 gload_lds) + 16 MFMA + read A-half1] BAR1 [16 MFMA].
// Slot safety: stage A(t+2) hits buf((t+2)%3)=buf(t-1), whose last reads
// (tile t-1 h1) are consumed (lgkm-waited) before each wave reaches BAR0(t);
// stage issues post-BAR0(t). A(t+2)'s stage loads are drained by every
// wave's compiler vmcnt wait on the NEWER B(t+1) frag loads (in-order
// retirement) before BAR1(t+1); buf(t+2) reads issue post-BAR1(t+1).
// T2 swizzle on A: chunk ^= row&7 (8 chunks of 16B per 128B row), applied as
// inverse-permuted global source on stage + XOR on ds_read (involution).

__device__ __forceinline__ void stage_tile32(const short* __restrict__ src,
                                             short* lds, int tid) {
#pragma unroll
  for (int c = 0; c < 4; ++c) {
    int idx = c * 512 + tid;
    int row = idx >> 3, c8 = idx & 7;
    int c8s = c8 ^ (row & 7);                     // inverse-swizzled source
    gload16(src + (size_t)row * KDIM + c8s * 8, lds + idx * 8);
  }
}

#define VMC(N) asm volatile("s_waitcnt vmcnt(" #N ")" ::: "memory")
#define BARR() __builtin_amdgcn_s_barrier();

#define READ_A32(DST, P, AB)                                                \
  _Pragma("unroll") for (int e = 0; e < 2; ++e)                             \
    _Pragma("unroll") for (int ks = 0; ks < 4; ++ks) {                      \
      int rw = (4 * (P) + 2 * e + wr) * 32 + l31;                           \
      DST[e][ks] = *(const bs8*)&AL[(AB) * 16384 + rw * 64 +                \
                    (((ks * 2 + hi) ^ (rw & 7)) * 8)];                      \
    }

// ks-outer: 4 accs rotate -> dep distance 4 (~128 cyc separation)
#define COMPUTE32(P)                                                        \
  __builtin_amdgcn_s_setprio(1);                                            \
  _Pragma("unroll") for (int ks = 0; ks < 4; ++ks)                          \
    _Pragma("unroll") for (int e = 0; e < 2; ++e)                           \
      _Pragma("unroll") for (int i = 0; i < 2; ++i)                         \
        acc[2 * (P) + e][i] = __builtin_amdgcn_mfma_f32_32x32x16_bf16(      \
            af[e][ks], bf[i][ks], acc[2 * (P) + e][i], 0, 0, 0);            \
  __builtin_amdgcn_s_setprio(0);

#define TILE(t, AB)                                                         \
  {                                                                         \
    bs8 bf[2][4], af[2][4];                                                 \
    _Pragma("unroll") for (int i = 0; i < 2; ++i)                           \
      _Pragma("unroll") for (int ks = 0; ks < 4; ++ks)                      \
        bf[i][ks] = *(const bs8*)(BTf + (size_t)i * (128 * KDIM) +          \
                                  (t) * 64 + ks * 16);                      \
    READ_A32(af, 0, AB);                                                    \
    BARR();                                                                 \
    if ((t) < KT - 2)                                                       \
      stage_tile32(Yb + ((t) + 2) * 64, AL + (((AB) + 2) % 3) * 16384, tid);\
    COMPUTE32(0);                                                           \
    READ_A32(af, 1, AB);                                                    \
    BARR();                                                                 \
    COMPUTE32(1);                                                           \
  }

__global__ __launch_bounds__(512, 2) void k_gemm(const short* __restrict__ Y,
                                                 const short* __restrict__ BT,
                                                 const float* __restrict__ x,
                                                 const float* __restrict__ bias,
                                                 float* __restrict__ out,
                                                 int b0, int nwg) {
  __shared__ __align__(16) short AL[3 * 16384];  // [3 bufs][256][64] 96 KiB

  int bid = blockIdx.x;
  int cpx = nwg >> 3;                        // nwg % 8 == 0 -> bijective
  int swz = (bid & 7) * cpx + (bid >> 3);    // XCD-aware swizzle
  int colb = swz & 3;                        // 4 col-blocks (N=1024/256)
  int rowb = swz >> 2;

  int tid = threadIdx.x;
  int lane = tid & 63, wave = tid >> 6;
  int wr = wave >> 2, wc = wave & 3;         // 2M x 4N waves
  int l31 = lane & 31, hi = lane >> 5;
  int row0 = rowb * 256, col0 = colb * 256;

  const short* Yb  = Y + (size_t)row0 * KDIM;
  const short* BTf = BT + (size_t)(col0 + wc * 32 + l31) * KDIM + hi * 8;

  f32x16 acc[4][2];                          // [2P+e][i]
#pragma unroll
  for (int j = 0; j < 4; ++j)
#pragma unroll
    for (int i = 0; i < 2; ++i)
#pragma unroll
      for (int q = 0; q < 16; ++q) acc[j][i][q] = 0.f;

  // prologue: A(0)->buf0, A(1)->buf1; drain A(0)
  stage_tile32(Yb,      AL,         tid);
  stage_tile32(Yb + 64, AL + 16384, tid);
  VMC(4);
  BARR();

  for (int t = 0; t < KT; t += 3) {
    TILE(t,     0);
    TILE(t + 1, 1);
    TILE(t + 2, 2);
  }

  // epilogue: out = relu(acc + bias[o] + x)
  // D-layout 32x32: col = lane&31, row = (q&3) + 8*(q>>2) + 4*(lane>>5)
#pragma unroll
  for (int P = 0; P < 2; ++P)
#pragma unroll
    for (int e = 0; e < 2; ++e) {
      int absf = 4 * P + 2 * e + wr;
#pragma unroll
      for (int q = 0; q < 16; ++q) {
        int r = row0 + absf * 32 + (q & 3) + 8 * (q >> 2) + 4 * hi;
        int o = r & 63;
        int btl = r >> 6;
        int tt = btl % NT;
        int bb = b0 + btl / NT;
        float bo = bias[o];
        size_t obase = ((size_t)(bb * 64 + o) * NT + tt) * NN;
#pragma unroll
        for (int i = 0; i < 2; ++i) {
          int n = col0 + (4 * i + wc) * 32 + l31;
          size_t oidx = obase + n;
          float v = acc[2 * P + e][i][q] + bo + x[oidx];
          out[oidx] = v > 0.f ? v : 0.f;
        }
      }
    }
}

extern "C" void kernel_launch(void* const* d_in, const int* in_sizes, int n_in,
                              void* d_out, int out_size, void* d_ws, size_t ws_size,
                              hipStream_t stream) {
  const float* x     = (const float*)d_in[0];
  const float* Lk    = (const float*)d_in[1];
  const float* theta = (const float*)d_in[2];
  const float* bias  = (const float*)d_in[3];
  float* out = (float*)d_out;

  char* ws = (char*)d_ws;
  short* BT = (short*)ws;                         // 6.29 MB
  short* Y  = (short*)(ws + (size_t)(8u << 20));  // up to 302 MB
  size_t avail = ws_size > ((size_t)8u << 20) ? ws_size - ((size_t)8u << 20) : 0;
  size_t perB = (size_t)NT * NC * KDIM * 2;       // 18,874,368 B per batch-row
  int bc = 16;
  while (bc > 1 && (size_t)bc * perB > avail) bc >>= 1;  // chunk over b if needed

  k_prep_bt<<<dim3(3072), dim3(256), 0, stream>>>(Lk, BT);
  for (int b0 = 0; b0 < NB; b0 += bc) {
    k_step1<<<dim3(bc * 384), dim3(256), 0, stream>>>(x, theta, Y, b0);
    int nwg = bc * 48;  // (bc*3072/256 rowb) * 4 colb, divisible by 8
    k_gemm<<<dim3(nwg), dim3(512), 0, stream>>>(Y, BT, x, bias, out, b0, nwg);
  }
}

// Round 10
// 483.454 us; speedup vs baseline: 1.4096x; 1.4096x over previous
//
#include <hip/hip_runtime.h>
#include <hip/hip_bf16.h>
#include <stdint.h>

// SpatioConvLayer: out = relu(x + b + einsum('iok,knm,bitm->botn', theta, Lk, x))
// (1) BT[n][k*1024+m] = bf16(Lk[k][n][m]); (2) Y[(b*48+t)*64+o][k*1024+m]
//     = sum_i theta[i,o,k] * x[b,i,t,m] (bf16, MFMA, LDS-staged x); (3) out =
//     Y @ BT^T fused bias+residual+relu, 256x256x64, 4 phases/K-tile, one
//     barrier per phase placed between reads and COMPUTE (R7 structure).
// R10: MFMA 32x32x16 (half the instrs, 2495 vs 2075 TF pipe), both operands
//      in LDS (R9 showed B-direct global is uncoalesced death), swizzle
//      g(row) = (row&7)^((row>>3)&3) keeps 16-lane groups 2-way conflict-free
//      for 32-row fragments.

typedef short bs8 __attribute__((ext_vector_type(8)));     // 8 x bf16 fragment
typedef float f32x4 __attribute__((ext_vector_type(4)));   // 16x16 accumulator
typedef float f32x16 __attribute__((ext_vector_type(16))); // 32x32 accumulator

#define NB   16
#define NC   64
#define NT   48
#define NN   1024
#define NKS  3
#define KDIM 3072  // NKS * NN
#define KT   48    // KDIM / 64 K-tiles

// f32 -> bf16 round-to-nearest-even (finite inputs only)
__device__ __forceinline__ short f2bs(float f) {
  uint32_t u = __builtin_bit_cast(uint32_t, f);
  u = (u + 0x7FFFu + ((u >> 16) & 1u)) >> 16;
  return (short)u;
}

__device__ __forceinline__ void gload16(const void* g, void* l) {
  __builtin_amdgcn_global_load_lds(
      (const __attribute__((address_space(1))) void*)g,
      (__attribute__((address_space(3))) void*)l, 16, 0, 0);
}

// ---------------- prep: BT[n][k*NN+m] = bf16(Lk[k][n][m]) -------------------
__global__ __launch_bounds__(256) void k_prep_bt(const float* __restrict__ Lk,
                                                 short* __restrict__ BT) {
  int gid = blockIdx.x * 256 + threadIdx.x;
  int e = gid * 4;
  int k = e >> 20;
  int rem = e & 1048575;
  int n = rem >> 10;
  int m = rem & 1023;
  float4 v = *reinterpret_cast<const float4*>(Lk + e);
  union { short s[4]; uint64_t u; } p;
  p.s[0] = f2bs(v.x); p.s[1] = f2bs(v.y); p.s[2] = f2bs(v.z); p.s[3] = f2bs(v.w);
  *reinterpret_cast<uint64_t*>(BT + (size_t)n * KDIM + k * NN + m) = p.u;
}

// ---------------- step1: Y[btl*64+o][k*NN+m] = sum_i th[i,o,k] x[b,i,t,m] ---
__global__ __launch_bounds__(256, 2) void k_step1(const float* __restrict__ x,
                                                  const float* __restrict__ theta,
                                                  short* __restrict__ Y, int b0) {
  __shared__ __align__(16) short th[NKS * 64 * 72];  // [k][o][i] padded, 27.6KB
  __shared__ __align__(16) float xs[64 * 128];       // [i][m] slice, 32KB
  int tid = threadIdx.x;
  int wave = tid >> 6;
  for (int idx = tid; idx < NC * NC * NKS; idx += 256) {
    int i = idx / (NC * NKS);
    int r = idx - i * (NC * NKS);
    int o = r / NKS;
    int k = r - o * NKS;
    th[(k * 64 + o) * 72 + i] = f2bs(theta[idx]);  // theta[i][o][k]
  }

  int bid = blockIdx.x;
  int mt  = bid & 7;            // m-tile of 128
  int btl = bid >> 3;
  int b_l = btl / NT;
  int t   = btl - b_l * NT;
  int b   = b0 + b_l;
  const float* xb = x + (size_t)b * (NC * NT * NN) + (size_t)t * NN + mt * 128;

#pragma unroll
  for (int c = 0; c < 8; ++c) {
    int idx = c * 256 + tid;
    int row = idx >> 5, ch = idx & 31;
    gload16(xb + (size_t)row * (NT * NN) + ch * 4,
            xs + (c * 256 + wave * 64) * 4);  // wave-uniform base, 16B/lane
  }
  __syncthreads();  // drains vmcnt (xs) + lgkm (th)

  int lane = tid & 63;
  int l15 = lane & 15, lg = lane >> 4;
  size_t yrow0 = (size_t)btl * 64;

  for (int nni = 0; nni < 2; ++nni) {
    int mloc = wave * 32 + nni * 16 + l15;
    float xv[16];
#pragma unroll
    for (int j = 0; j < 16; ++j) {
      int i = ((j >> 3) << 5) + lg * 8 + (j & 7);
      xv[j] = xs[i * 128 + mloc];
    }
    f32x4 acc[3][4];
#pragma unroll
    for (int k = 0; k < 3; ++k)
#pragma unroll
      for (int mi = 0; mi < 4; ++mi)
        acc[k][mi] = (f32x4){0.f, 0.f, 0.f, 0.f};

#pragma unroll
    for (int ks = 0; ks < 2; ++ks) {
      bs8 bfrag;
#pragma unroll
      for (int j = 0; j < 8; ++j) bfrag[j] = f2bs(xv[ks * 8 + j]);
#pragma unroll
      for (int mi = 0; mi < 4; ++mi) {
#pragma unroll
        for (int k = 0; k < 3; ++k) {
          const bs8* ap = reinterpret_cast<const bs8*>(
              &th[(k * 64 + mi * 16 + l15) * 72 + ks * 32 + lg * 8]);
          acc[k][mi] = __builtin_amdgcn_mfma_f32_16x16x32_bf16(
              *ap, bfrag, acc[k][mi], 0, 0, 0);
        }
      }
    }
    int mcol = mt * 128 + mloc;
#pragma unroll
    for (int k = 0; k < 3; ++k)
#pragma unroll
      for (int mi = 0; mi < 4; ++mi)
#pragma unroll
        for (int q = 0; q < 4; ++q) {
          int o = mi * 16 + lg * 4 + q;
          Y[(yrow0 + o) * KDIM + k * NN + mcol] = f2bs(acc[k][mi][q]);
        }
  }
}

// ---------------- big GEMM: C = Y @ BT^T, 256^2, 32x32x16, LDS both ---------
// 8 waves 2M x 4N (wr = wave>>2, wc = wave&3). Wave out 128x64: M-frags(32)
// mf = 2a+wr (a=0..3, pairs MP: mf = 4MP+2e+wr), N-frags(32) nf = 4i+wc.
// Phase order (MP,NI) = (0,0)->(0,1)->(1,1)->(1,0); frag reuse: af read at
// P0/P2 (8 b128), bf0 at P0 (4, held to P3), bf1 at P1 (4, reused P2).
// 24 ds_read/tile/wave, 32 MFMA/tile/wave. Stream per phase: reads; stage;
// BAR; COMPUTE (one barrier; COMPUTE(k) and reads(k+1) unseparated so the
// scheduler can interleave). Stage schedule and vmcnt(4)/tile = R7 verbatim
// (slot-overwrite gaps >= 2 barriers, ledger in R5/R7 comments).
// Swizzle: LDS[row][c8] = global[row][c8 ^ g(row)], g = (row&7)^((row>>3)&3);
// reader XORs the same g. Within any 16-lane HW group, 2 lanes/chunk (free).

__device__ __forceinline__ void stage_half(const short* __restrict__ src,
                                           short* lds, int h, int tid) {
  int wave = tid >> 6;
#pragma unroll
  for (int r = 0; r < 2; ++r) {
    int idx = h * 1024 + r * 512 + tid;
    int row = idx >> 3, c8 = idx & 7;
    int c8s = c8 ^ (row & 7) ^ ((row >> 3) & 3);  // inverse-swizzled source
    gload16(src + (size_t)row * KDIM + c8s * 8,
            lds + (h * 1024 + r * 512 + wave * 64) * 8);  // wave-uniform base
  }
}

#define VMC(N) asm volatile("s_waitcnt vmcnt(" #N ")" ::: "memory")
#define BARR() __builtin_amdgcn_s_barrier();

#define READ_A32(DST, MP, P)                                                \
  _Pragma("unroll") for (int e = 0; e < 2; ++e)                             \
    _Pragma("unroll") for (int ks = 0; ks < 4; ++ks) {                      \
      int row = (4 * (MP) + 2 * e + wr) * 32 + l31;                         \
      int ch = (2 * ks + hi) ^ (row & 7) ^ ((row >> 3) & 3);                \
      DST[e][ks] = *(const bs8*)&AL[(P) * 16384 + row * 64 + ch * 8];       \
    }

#define READ_B32(DST, NI, P)                                                \
  _Pragma("unroll") for (int ks = 0; ks < 4; ++ks) {                        \
    int row = (4 * (NI) + wc) * 32 + l31;                                   \
    int ch = (2 * ks + hi) ^ (row & 7) ^ ((row >> 3) & 3);                  \
    DST[ks] = *(const bs8*)&BL[(P) * 16384 + row * 64 + ch * 8];            \
  }

// ks-outer: the 2 accs of a phase rotate (dep distance 2, ~130 cyc)
#define COMPUTE32(MP, BF, NI)                                               \
  __builtin_amdgcn_s_setprio(1);                                            \
  _Pragma("unroll") for (int ks = 0; ks < 4; ++ks)                          \
    _Pragma("unroll") for (int e = 0; e < 2; ++e)                           \
      acc[2 * (MP) + e][(NI)] = __builtin_amdgcn_mfma_f32_32x32x16_bf16(    \
          af[e][ks], BF[ks], acc[2 * (MP) + e][(NI)], 0, 0, 0);             \
  __builtin_amdgcn_s_setprio(0);

// S1: t+1 exists (stage A1/B1); S2: t+2 exists (stage A0/B0); VM: tile vmcnt.
#define TILE(t, P, S1, S2, VM)                                              \
  {                                                                         \
    bs8 af[2][4], bf0[4], bf1[4];                                           \
    READ_A32(af, 0, P);                                                     \
    READ_B32(bf0, 0, P);                                                    \
    if (S1) stage_half(Yb + ((t) + 1) * 64, AL + ((P) ^ 1) * 16384, 1, tid);\
    BARR();                                                                 \
    COMPUTE32(0, bf0, 0);                                                   \
    READ_B32(bf1, 1, P);                                                    \
    if (S1) stage_half(BTb + ((t) + 1) * 64, BL + ((P) ^ 1) * 16384, 1, tid);\
    BARR();                                                                 \
    COMPUTE32(0, bf1, 1);                                                   \
    READ_A32(af, 1, P);                                                     \
    if (S2) stage_half(Yb + ((t) + 2) * 64, AL + (P) * 16384, 0, tid);      \
    BARR();                                                                 \
    COMPUTE32(1, bf1, 1);                                                   \
    if (S2) stage_half(BTb + ((t) + 2) * 64, BL + (P) * 16384, 0, tid);     \
    VM;                                                                     \
    BARR();                                                                 \
    COMPUTE32(1, bf0, 0);                                                   \
  }

__global__ __launch_bounds__(512, 2) void k_gemm(const short* __restrict__ Y,
                                                 const short* __restrict__ BT,
                                                 const float* __restrict__ x,
                                                 const float* __restrict__ bias,
                                                 float* __restrict__ out,
                                                 int b0, int nwg) {
  __shared__ __align__(16) short AL[2 * 16384];  // [buf][256][64] 64 KiB
  __shared__ __align__(16) short BL[2 * 16384];  // [buf][256][64] 64 KiB

  int bid = blockIdx.x;
  int cpx = nwg >> 3;                        // nwg % 8 == 0 -> bijective
  int swz = (bid & 7) * cpx + (bid >> 3);    // XCD-aware swizzle
  int colb = swz & 3;                        // 4 col-blocks (N=1024/256)
  int rowb = swz >> 2;

  int tid = threadIdx.x;
  int lane = tid & 63, wave = tid >> 6;
  int wr = wave >> 2, wc = wave & 3;         // 2M x 4N waves
  int l31 = lane & 31, hi = lane >> 5;
  int row0 = rowb * 256, col0 = colb * 256;

  const short* Yb  = Y  + (size_t)row0 * KDIM;
  const short* BTb = BT + (size_t)col0 * KDIM;

  f32x16 acc[4][2];                          // [a = 2MP+e][NI]; mf = 2a+wr
#pragma unroll
  for (int a = 0; a < 4; ++a)
#pragma unroll
    for (int i = 0; i < 2; ++i)
#pragma unroll
      for (int q = 0; q < 16; ++q) acc[a][i][q] = 0.f;

  // prologue: tile0 (A0,A1,B0,B1) -> buf0; A0(1),B0(1) -> buf1 (12 loads)
  stage_half(Yb,        AL,         0, tid);
  stage_half(Yb,        AL,         1, tid);
  stage_half(BTb,       BL,         0, tid);
  stage_half(BTb,       BL,         1, tid);
  stage_half(Yb + 64,   AL + 16384, 0, tid);
  stage_half(BTb + 64,  BL + 16384, 0, tid);
  VMC(4);                                    // tile0 landed; {A0,B0}(1) fly
  BARR();

  for (int t = 0; t < KT - 2; t += 2) {
    TILE(t,     0, 1, 1, VMC(4));
    TILE(t + 1, 1, 1, 1, VMC(4));
  }
  TILE(KT - 2, 0, 1, 0, VMC(0));
  TILE(KT - 1, 1, 0, 0, (void)0);

  // epilogue: out = relu(acc + bias[o] + x)
  // 32x32 D-layout: col = lane&31, row = (q&3) + 8*(q>>2) + 4*(lane>>5)
#pragma unroll
  for (int a = 0; a < 4; ++a) {
    int mf = 2 * a + wr;
#pragma unroll
    for (int q = 0; q < 16; ++q) {
      int r = row0 + mf * 32 + (q & 3) + 8 * (q >> 2) + 4 * hi;
      int o = r & 63;
      int btl = r >> 6;
      int tt = btl % NT;
      int bb = b0 + btl / NT;
      float bo = bias[o];
      size_t obase = ((size_t)(bb * 64 + o) * NT + tt) * NN;
#pragma unroll
      for (int i = 0; i < 2; ++i) {
        int n = col0 + (4 * i + wc) * 32 + l31;
        size_t oidx = obase + n;
        float v = acc[a][i][q] + bo + x[oidx];
        out[oidx] = v > 0.f ? v : 0.f;
      }
    }
  }
}

extern "C" void kernel_launch(void* const* d_in, const int* in_sizes, int n_in,
                              void* d_out, int out_size, void* d_ws, size_t ws_size,
                              hipStream_t stream) {
  const float* x     = (const float*)d_in[0];
  const float* Lk    = (const float*)d_in[1];
  const float* theta = (const float*)d_in[2];
  const float* bias  = (const float*)d_in[3];
  float* out = (float*)d_out;

  char* ws = (char*)d_ws;
  short* BT = (short*)ws;                         // 6.29 MB
  short* Y  = (short*)(ws + (size_t)(8u << 20));  // up to 302 MB
  size_t avail = ws_size > ((size_t)8u << 20) ? ws_size - ((size_t)8u << 20) : 0;
  size_t perB = (size_t)NT * NC * KDIM * 2;       // 18,874,368 B per batch-row
  int bc = 16;
  while (bc > 1 && (size_t)bc * perB > avail) bc >>= 1;  // chunk over b if needed

  k_prep_bt<<<dim3(3072), dim3(256), 0, stream>>>(Lk, BT);
  for (int b0 = 0; b0 < NB; b0 += bc) {
    k_step1<<<dim3(bc * 384), dim3(256), 0, stream>>>(x, theta, Y, b0);
    int nwg = bc * 48;  // (bc*3072/256 rowb) * 4 colb, divisible by 8
    k_gemm<<<dim3(nwg), dim3(512), 0, stream>>>(Y, BT, x, bias, out, b0, nwg);
  }
}